// Round 5
// baseline (148.073 us; speedup 1.0000x reference)
//
#include <hip/hip_runtime.h>
#include <hip/hip_cooperative_groups.h>

#define DD 128
#define NN 512

namespace cg = cooperative_groups;

// ---------------------------------------------------------------------------
// Single cooperative kernel, 256 blocks x 256 threads, 8 adj-rows per block.
//
// stage 1a (all blocks): popcount own 8 adj rows -> s_p[r]        (HBM 4.2 MB)
// stage 1b (blocks 0..19): distributed prep:
//     cb[b][d] = b1[d] + E0@W1a + nc@W1b + te[t[b]]@W1c   (blocks 0..15,
//         quarter-k partials -> ws_cbq[q][b][d]; x-vector loads are
//         wave-uniform => scalar loads + broadcast)
//     v1[d]    = (E1-E0)@W1a                              (blocks 16..19,
//         quarter-k partials -> ws_v1q[q][d])
// grid.sync()
// stage 2 (all blocks): h[d] = relu(cb[d] + p[r]*v1[d]);  preHf = h @ W2;
//     Hf = relu(preHf + b2);  li/lj = Hf @ Wc halves (+bc folded into li).
//     W2 read once per block (64 KB from L2); d-split 8x16 across waves,
//     partials combined in LDS.
// grid.sync()
// stage 3 (all blocks): out[b,i,j,:] = li[b,i,:] + lj[b,j,:] for own 8 rows.
//     Per-instruction coalesced float4 stores (lane cg -> float4 idx cg+32k).
// ---------------------------------------------------------------------------
__global__ __launch_bounds__(256) void fused_kernel(
    const int* __restrict__ adj,
    const int* __restrict__ tt,
    const float* __restrict__ time_embed,
    const float* __restrict__ no_cond,
    const float* __restrict__ edge_embed,
    const float* __restrict__ W1,
    const float* __restrict__ b1,
    const float* __restrict__ W2,
    const float* __restrict__ b2,
    const float* __restrict__ Wc,
    const float* __restrict__ bc,
    float* __restrict__ ws_cbq,   // [4 q][4 b][128]
    float* __restrict__ ws_v1q,   // [4 q][128]
    float* __restrict__ ws_li,    // [2048*2] (bc pre-added)
    float* __restrict__ ws_lj,    // [2048*2]
    float* __restrict__ out)      // [4,512,512,2]
{
    cg::grid_group grid = cg::this_grid();

    __shared__ float sP[8 * 8 * DD];   // 32 KB partial preHf [r][dh][c]
    __shared__ float s_cb[DD];
    __shared__ float s_v1[DD];
    __shared__ float s_p[8];
    __shared__ float s_red[256];

    const int t    = threadIdx.x;
    const int blk  = blockIdx.x;
    const int row0 = blk * 8;
    const int b    = blk >> 6;
    const int lane = t & 31;     // 0..31 within half-wave group
    const int dh   = t >> 5;     // 0..7  (row / d-chunk selector)

    // ---- stage 1a: popcount own 8 rows --------------------------------
    {
        const int4* base = (const int4*)(adj + (size_t)(row0 + dh) * NN);
        int s = 0;
#pragma unroll
        for (int k = 0; k < 4; ++k) {
            int4 a = base[lane + 32 * k];
            s += a.x + a.y + a.z + a.w;
        }
#pragma unroll
        for (int off = 16; off; off >>= 1) s += __shfl_xor(s, off, 64);
        if (lane == 0) s_p[dh] = (float)s * (1.0f / (float)NN);
    }

    // ---- stage 1b: distributed prep partials --------------------------
    if (blk < 16) {
        const int pb = blk >> 2;     // batch 0..3
        const int q  = blk & 3;      // k-quarter 0..3 of concat x[384]
        const int d  = t & 127;
        const int h  = t >> 7;
        const float* teb = time_embed + (size_t)tt[pb] * DD;
        const int k0 = q * 96 + h * 48;
        float c = 0.f;
#pragma unroll
        for (int kk = 0; kk < 48; ++kk) {
            const int k = k0 + kk;   // wave-uniform -> scalar load of xv
            float xv = (k < 128) ? edge_embed[k]
                     : (k < 256) ? no_cond[k - 128]
                                 : teb[k - 256];
            c = fmaf(xv, W1[k * DD + d], c);
        }
        s_red[t] = c;
        __syncthreads();
        if (t < 128)
            ws_cbq[(q * 4 + pb) * DD + t] = s_red[t] + s_red[t + 128];
    } else if (blk < 20) {
        const int q = blk - 16;      // k-quarter 0..3 of 128
        const int d = t & 127;
        const int h = t >> 7;
        const int k0 = q * 32 + h * 16;
        float c = 0.f;
#pragma unroll
        for (int kk = 0; kk < 16; ++kk) {
            const int k = k0 + kk;
            c = fmaf(edge_embed[DD + k] - edge_embed[k], W1[k * DD + d], c);
        }
        s_red[t] = c;
        __syncthreads();
        if (t < 128)
            ws_v1q[q * DD + t] = s_red[t] + s_red[t + 128];
    }

    grid.sync();

    // ---- stage 2: MLP + classifier for own 8 rows ---------------------
    if (t < DD) {
        float c = b1[t];
        float v = 0.f;
#pragma unroll
        for (int q = 0; q < 4; ++q) {
            c += ws_cbq[(q * 4 + b) * DD + t];
            v += ws_v1q[q * DD + t];
        }
        s_cb[t] = c;
        s_v1[t] = v;
    }
    __syncthreads();

    float p[8];
#pragma unroll
    for (int r = 0; r < 8; ++r) p[r] = s_p[r];

    const int c0 = lane * 4;
    float acc[8][4];
#pragma unroll
    for (int r = 0; r < 8; ++r)
#pragma unroll
        for (int cc = 0; cc < 4; ++cc) acc[r][cc] = 0.f;

    const float4* W2v = (const float4*)W2;
#pragma unroll
    for (int i = 0; i < 16; ++i) {
        const int d = dh * 16 + i;
        float4 w = W2v[(d * DD + c0) >> 2];
        float cbd = s_cb[d];
        float v1d = s_v1[d];
#pragma unroll
        for (int r = 0; r < 8; ++r) {
            float h = fmaxf(fmaf(p[r], v1d, cbd), 0.f);
            acc[r][0] = fmaf(h, w.x, acc[r][0]);
            acc[r][1] = fmaf(h, w.y, acc[r][1]);
            acc[r][2] = fmaf(h, w.z, acc[r][2]);
            acc[r][3] = fmaf(h, w.w, acc[r][3]);
        }
    }
#pragma unroll
    for (int r = 0; r < 8; ++r) {
        float4 v = make_float4(acc[r][0], acc[r][1], acc[r][2], acc[r][3]);
        *(float4*)&sP[(r * 8 + dh) * DD + c0] = v;
    }
    __syncthreads();

    {
        float s0 = 0.f, s1 = 0.f, s2 = 0.f, s3 = 0.f;
#pragma unroll
        for (int k = 0; k < 8; ++k) {
            float4 v = *(const float4*)&sP[(dh * 8 + k) * DD + c0];
            s0 += v.x; s1 += v.y; s2 += v.z; s3 += v.w;
        }
        float4 bb = *(const float4*)&b2[c0];
        float f0 = fmaxf(s0 + bb.x, 0.f);
        float f1 = fmaxf(s1 + bb.y, 0.f);
        float f2 = fmaxf(s2 + bb.z, 0.f);
        float f3 = fmaxf(s3 + bb.w, 0.f);

        const float4* WcV = (const float4*)Wc;
        float4 wa0 = WcV[(c0 * 2) >> 2];
        float4 wa1 = WcV[(c0 * 2 + 4) >> 2];
        float4 wb0 = WcV[((DD + c0) * 2) >> 2];
        float4 wb1 = WcV[((DD + c0) * 2 + 4) >> 2];

        float li0 = f0 * wa0.x + f1 * wa0.z + f2 * wa1.x + f3 * wa1.z;
        float li1 = f0 * wa0.y + f1 * wa0.w + f2 * wa1.y + f3 * wa1.w;
        float lj0 = f0 * wb0.x + f1 * wb0.z + f2 * wb1.x + f3 * wb1.z;
        float lj1 = f0 * wb0.y + f1 * wb0.w + f2 * wb1.y + f3 * wb1.w;

#pragma unroll
        for (int off = 16; off; off >>= 1) {
            li0 += __shfl_xor(li0, off, 64);
            li1 += __shfl_xor(li1, off, 64);
            lj0 += __shfl_xor(lj0, off, 64);
            lj1 += __shfl_xor(lj1, off, 64);
        }
        if (lane == 0) {
            int row = row0 + dh;
            *(float2*)&ws_li[row * 2] = make_float2(li0 + bc[0], li1 + bc[1]);
            *(float2*)&ws_lj[row * 2] = make_float2(lj0, lj1);
        }
    }

    grid.sync();

    // ---- stage 3: broadcast write of own 8 rows -----------------------
    {
        const float4* ljv = (const float4*)(ws_lj + (size_t)b * NN * 2); // 256 x float4
        const int r   = t >> 5;            // 0..7
        const int row = row0 + r;          // global row (includes b*512)
        float2 li = *(const float2*)&ws_li[row * 2];
        const float a0 = li.x, a1 = li.y;
        float4* orow = (float4*)(out + (size_t)row * NN * 2);
#pragma unroll
        for (int k = 0; k < 8; ++k) {
            const int q = lane + 32 * k;   // float4 index 0..255, coalesced
            float4 L = ljv[q];
            orow[q] = make_float4(a0 + L.x, a1 + L.y, a0 + L.z, a1 + L.w);
        }
    }
}

extern "C" void kernel_launch(void* const* d_in, const int* in_sizes, int n_in,
                              void* d_out, int out_size, void* d_ws, size_t ws_size,
                              hipStream_t stream) {
    const int*   adj = (const int*)d_in[0];
    const int*   tt  = (const int*)d_in[1];
    const float* te  = (const float*)d_in[2];
    const float* nc  = (const float*)d_in[3];
    const float* ee  = (const float*)d_in[4];
    const float* W1  = (const float*)d_in[5];
    const float* b1  = (const float*)d_in[6];
    const float* W2  = (const float*)d_in[7];
    const float* b2  = (const float*)d_in[8];
    const float* Wc  = (const float*)d_in[9];
    const float* bc  = (const float*)d_in[10];
    float* out = (float*)d_out;

    float* ws     = (float*)d_ws;
    float* ws_cbq = ws;            // 2048 floats
    float* ws_v1q = ws + 2048;     // 512 floats
    float* ws_li  = ws + 2560;     // 4096 floats
    float* ws_lj  = ws + 6656;     // 4096 floats

    void* args[] = { (void*)&adj, (void*)&tt, (void*)&te, (void*)&nc,
                     (void*)&ee, (void*)&W1, (void*)&b1, (void*)&W2,
                     (void*)&b2, (void*)&Wc, (void*)&bc,
                     (void*)&ws_cbq, (void*)&ws_v1q, (void*)&ws_li,
                     (void*)&ws_lj, (void*)&out };
    hipLaunchCooperativeKernel((const void*)fused_kernel,
                               dim3(256), dim3(256), args, 0, stream);
}

// Round 6
// 98.850 us; speedup vs baseline: 1.4979x; 1.4979x over previous
//
#include <hip/hip_runtime.h>
#include <hip/hip_bf16.h>

#define DD 128
#define NN 512
#define BB 4

// ---------------------------------------------------------------------------
// Kernel 1: fused prep + per-row pipeline. 256 blocks x 256 threads, 8 rows/blk.
//  phase A0: issue adj HBM loads first (latency overlapped with phase P).
//  phase P: each block redundantly computes cb[b][d] and v1[d] from W1 (L2).
//  phase A1: popcount reduce -> p[r].
//  phase B: preHf[r][c] = sum_d relu(cb[d]+p[r]*v1[d]) * W2[d][c]
//  phase C: combine partials in LDS, relu(+b2), project onto Wc -> li/lj;
//           bc folded into li.
// ---------------------------------------------------------------------------
__global__ __launch_bounds__(256) void rows_kernel(
    const int* __restrict__ adj,
    const int* __restrict__ tt,
    const float* __restrict__ time_embed,
    const float* __restrict__ no_cond,
    const float* __restrict__ edge_embed,
    const float* __restrict__ W1,
    const float* __restrict__ b1,
    const float* __restrict__ W2,
    const float* __restrict__ b2,
    const float* __restrict__ Wc,
    const float* __restrict__ bc,
    float* __restrict__ ws_li,   // [2048*2]  (bc pre-added)
    float* __restrict__ ws_lj)   // [2048*2]
{
    __shared__ float sP[8 * 8 * DD];   // [r][dh][c] partial preHf, 32 KB
    __shared__ float s_cb[DD];
    __shared__ float s_v1[DD];
    __shared__ float s_p[8];
    __shared__ float s_rc[256];
    __shared__ float s_rv[256];

    const int t = threadIdx.x;
    const int row0 = blockIdx.x * 8;
    const int b = blockIdx.x >> 6;

    const int cg = t & 31;    // 0..31
    const int dh = t >> 5;    // 0..7

    // --- phase A0: issue adj loads early (HBM latency hides under phase P) ---
    const int4* abase = (const int4*)(adj + (size_t)(row0 + dh) * NN);
    int4 av0 = abase[cg];
    int4 av1 = abase[cg + 32];
    int4 av2 = abase[cg + 64];
    int4 av3 = abase[cg + 96];

    // --- phase P: partial cb / v1 (h = wave-uniform half selector) ---
    {
        const int d = t & 127;
        const int h = t >> 7;
        const float* teb = time_embed + (size_t)tt[b] * DD;
        float c = 0.f, v = 0.f;
        if (h == 0) {
#pragma unroll 4
            for (int k = 0; k < 128; ++k)
                c = fmaf(edge_embed[k], W1[k * DD + d], c);
#pragma unroll 4
            for (int k = 0; k < 64; ++k)
                c = fmaf(no_cond[k], W1[(128 + k) * DD + d], c);
#pragma unroll 4
            for (int k = 64; k < 128; ++k)
                v = fmaf(edge_embed[DD + k] - edge_embed[k], W1[k * DD + d], v);
        } else {
#pragma unroll 4
            for (int k = 64; k < 128; ++k)
                c = fmaf(no_cond[k], W1[(128 + k) * DD + d], c);
#pragma unroll 4
            for (int k = 0; k < 128; ++k)
                c = fmaf(teb[k], W1[(256 + k) * DD + d], c);
#pragma unroll 4
            for (int k = 0; k < 64; ++k)
                v = fmaf(edge_embed[DD + k] - edge_embed[k], W1[k * DD + d], v);
        }
        s_rc[t] = c;
        s_rv[t] = v;
    }

    // --- phase A1: popcount reduce ---
    {
        int s = av0.x + av0.y + av0.z + av0.w
              + av1.x + av1.y + av1.z + av1.w
              + av2.x + av2.y + av2.z + av2.w
              + av3.x + av3.y + av3.z + av3.w;
#pragma unroll
        for (int off = 16; off; off >>= 1) s += __shfl_xor(s, off, 64);
        if (cg == 0) s_p[dh] = (float)s * (1.0f / (float)NN);
    }
    __syncthreads();

    if (t < DD) {
        s_cb[t] = s_rc[t] + s_rc[t + 128] + b1[t];
        s_v1[t] = s_rv[t] + s_rv[t + 128];
    }
    __syncthreads();

    float p[8];
#pragma unroll
    for (int r = 0; r < 8; ++r) p[r] = s_p[r];

    // --- phase B: partial matvec. thread = (col group cg -> c0..c0+3, d chunk dh) ---
    const int c0 = cg * 4;
    float acc[8][4];
#pragma unroll
    for (int r = 0; r < 8; ++r)
#pragma unroll
        for (int cc = 0; cc < 4; ++cc) acc[r][cc] = 0.f;

    const float4* W2v = (const float4*)W2;
#pragma unroll
    for (int i = 0; i < 16; ++i) {
        const int d = dh * 16 + i;
        float4 w = W2v[(d * DD + c0) >> 2];
        float cbd = s_cb[d];
        float v1d = s_v1[d];
#pragma unroll
        for (int r = 0; r < 8; ++r) {
            float h = fmaxf(fmaf(p[r], v1d, cbd), 0.f);
            acc[r][0] = fmaf(h, w.x, acc[r][0]);
            acc[r][1] = fmaf(h, w.y, acc[r][1]);
            acc[r][2] = fmaf(h, w.z, acc[r][2]);
            acc[r][3] = fmaf(h, w.w, acc[r][3]);
        }
    }
#pragma unroll
    for (int r = 0; r < 8; ++r) {
        float4 v = make_float4(acc[r][0], acc[r][1], acc[r][2], acc[r][3]);
        *(float4*)&sP[(r * 8 + dh) * DD + c0] = v;
    }
    __syncthreads();

    // --- phase C: combine.  thread -> (row = dh, cols c0..c0+3) ---
    float s0 = 0.f, s1 = 0.f, s2 = 0.f, s3 = 0.f;
#pragma unroll
    for (int k = 0; k < 8; ++k) {
        float4 v = *(const float4*)&sP[(dh * 8 + k) * DD + c0];
        s0 += v.x; s1 += v.y; s2 += v.z; s3 += v.w;
    }
    float4 bb = *(const float4*)&b2[c0];
    float f0 = fmaxf(s0 + bb.x, 0.f);
    float f1 = fmaxf(s1 + bb.y, 0.f);
    float f2 = fmaxf(s2 + bb.z, 0.f);
    float f3 = fmaxf(s3 + bb.w, 0.f);

    const float4* WcV = (const float4*)Wc;
    float4 wa0 = WcV[(c0 * 2) >> 2];            // Wc rows c0, c0+1
    float4 wa1 = WcV[(c0 * 2 + 4) >> 2];        // Wc rows c0+2, c0+3
    float4 wb0 = WcV[((DD + c0) * 2) >> 2];
    float4 wb1 = WcV[((DD + c0) * 2 + 4) >> 2];

    float li0 = f0 * wa0.x + f1 * wa0.z + f2 * wa1.x + f3 * wa1.z;
    float li1 = f0 * wa0.y + f1 * wa0.w + f2 * wa1.y + f3 * wa1.w;
    float lj0 = f0 * wb0.x + f1 * wb0.z + f2 * wb1.x + f3 * wb1.z;
    float lj1 = f0 * wb0.y + f1 * wb0.w + f2 * wb1.y + f3 * wb1.w;

#pragma unroll
    for (int off = 16; off; off >>= 1) {
        li0 += __shfl_xor(li0, off, 64);
        li1 += __shfl_xor(li1, off, 64);
        lj0 += __shfl_xor(lj0, off, 64);
        lj1 += __shfl_xor(lj1, off, 64);
    }
    if (cg == 0) {
        int row = row0 + dh;
        *(float2*)&ws_li[row * 2] = make_float2(li0 + bc[0], li1 + bc[1]);
        *(float2*)&ws_lj[row * 2] = make_float2(lj0, lj1);
    }
}

// ---------------------------------------------------------------------------
// Kernel 2: logits[b,i,j,c] = li[b,i,c] + lj[b,j,c]   (bc pre-folded into li)
// Grid: 1024 blocks x 256 threads. Block covers 2 i-rows; thread stores 8 f32.
// ---------------------------------------------------------------------------
__global__ __launch_bounds__(256) void write_kernel(
    const float* __restrict__ ws_li,
    const float* __restrict__ ws_lj,
    float* __restrict__ out)
{
    const int blk = blockIdx.x;           // 0..1023
    const int t = threadIdx.x;
    const int b = blk >> 8;
    const int i = (blk & 255) * 2 + (t >> 7);
    const int j0 = (t & 127) * 4;

    float2 li = *(const float2*)&ws_li[(b * NN + i) * 2];
    float a0 = li.x;
    float a1 = li.y;

    float4 L0 = *(const float4*)&ws_lj[(b * NN + j0) * 2];       // rows j0, j0+1
    float4 L1 = *(const float4*)&ws_lj[(b * NN + j0 + 2) * 2];   // rows j0+2, j0+3

    float4 o0 = make_float4(a0 + L0.x, a1 + L0.y, a0 + L0.z, a1 + L0.w);
    float4 o1 = make_float4(a0 + L1.x, a1 + L1.y, a0 + L1.z, a1 + L1.w);

    size_t base = (((size_t)(b * NN + i)) * NN + j0) * 2;   // f32 element index
    *(float4*)&out[base]     = o0;
    *(float4*)&out[base + 4] = o1;
}

extern "C" void kernel_launch(void* const* d_in, const int* in_sizes, int n_in,
                              void* d_out, int out_size, void* d_ws, size_t ws_size,
                              hipStream_t stream) {
    const int*   adj = (const int*)d_in[0];
    const int*   tt  = (const int*)d_in[1];
    const float* te  = (const float*)d_in[2];
    const float* nc  = (const float*)d_in[3];
    const float* ee  = (const float*)d_in[4];
    const float* W1  = (const float*)d_in[5];
    const float* b1  = (const float*)d_in[6];
    const float* W2  = (const float*)d_in[7];
    const float* b2  = (const float*)d_in[8];
    const float* Wc  = (const float*)d_in[9];
    const float* bc  = (const float*)d_in[10];
    float* out = (float*)d_out;

    float* ws    = (float*)d_ws;
    float* ws_li = ws;            // 4096 floats
    float* ws_lj = ws + 4096;     // 4096 floats

    rows_kernel<<<256, 256, 0, stream>>>(adj, tt, te, nc, ee, W1, b1, W2, b2,
                                         Wc, bc, ws_li, ws_lj);
    write_kernel<<<1024, 256, 0, stream>>>(ws_li, ws_lj, out);
}